// Round 2
// baseline (440.209 us; speedup 1.0000x reference)
//
#include <hip/hip_runtime.h>
#include <stdint.h>

// ---------------------------------------------------------------------------
// MLP_Model: candidates head + per-route Customer MLP + 2-layer GRU + FC head
// R5 (resubmit; previous round failed on container acquisition, not kernel):
// operand-swapped MFMAs (weights as A, activations as B) so D is
// transposed: each lane holds 4 CONSECUTIVE hidden units of one sequence.
// Epilogues become 2x v_cvt_pk_bf16_f32 + ds_write_b64 (was 8x f2bf +
// 8x scalar ds_write_b16 with 4-8 way bank conflicts), biases become float4
// vector loads, hout store becomes dwordx4, mlp x2 store becomes b64.
// pack_weights unchanged: A-frag and B-frag share the same (lane,j)->(idx,k)
// mapping, so the packed weights are valid as A-operands as-is.
// ws layout: [0,344064) packed bf16 weights; [344064,38092800) x2 bf16;
// [38092800,...) h1 final fp32 (~50.7 MB total).
// ---------------------------------------------------------------------------

#define NSEQ   24576   // 512 * 48
#define TSTEPS 24

typedef __attribute__((ext_vector_type(8))) short bf16x8;
typedef __attribute__((ext_vector_type(4))) float floatx4;

// packed-weight element offsets (uint16 units)
#define PK_W1    0
#define PK_W2    8192
#define PK_WIH0  12288
#define PK_WHH0  24576
#define PK_WIH1  73728
#define PK_WHH1  122880
#define PK_END   172032
#define X2_EL    172032                 // x2: [t][seq][32] bf16
#define HOUT_BYTE 38092800              // h1 final: [seq][128] fp32

#define MFMA(a,b,c) c = __builtin_amdgcn_mfma_f32_16x16x32_bf16(a, b, c, 0, 0, 0)

__device__ __forceinline__ uint16_t f2bf(float f) {
  uint32_t u = __float_as_uint(f);
  u += 0x7FFFu + ((u >> 16) & 1u);           // RNE
  return (uint16_t)(u >> 16);
}
// packed f32x2 -> bf16x2 (RNE), single VALU op. lo half = first arg.
__device__ __forceinline__ uint32_t cvt_pk(float a, float b) {
  uint32_t r;
  asm("v_cvt_pk_bf16_f32 %0, %1, %2" : "=v"(r) : "v"(a), "v"(b));
  return r;
}
__device__ __forceinline__ float fast_sigmoid(float x) {
  float e = __builtin_amdgcn_exp2f(-1.4426950408889634f * x);
  return __builtin_amdgcn_rcpf(1.0f + e);
}
__device__ __forceinline__ float fast_tanh(float x) {
  float e = __builtin_amdgcn_exp2f(-2.8853900817779268f * x);
  return 2.0f * __builtin_amdgcn_rcpf(1.0f + e) - 1.0f;
}
__device__ __forceinline__ bf16x8 ldf(const uint16_t* p) {
  return *(const bf16x8*)p;
}

// ---------------------------------------------------------------------------
// Kernel 0: pack all weights to bf16 fragment layout. (unchanged — the
// layout is simultaneously a valid B-frag (n=lane&15) and A-frag (m=lane&15))
// ---------------------------------------------------------------------------
__global__ __launch_bounds__(256) void pack_weights(
    const float* __restrict__ w1, const float* __restrict__ w2,
    const float* __restrict__ wih0, const float* __restrict__ whh0,
    const float* __restrict__ wih1, const float* __restrict__ whh1,
    uint16_t* __restrict__ ws) {
  int idx = blockIdx.x * 256 + threadIdx.x;
  if (idx >= PK_END) return;
  const float* W; int N, KB, Kreal, base;
  if      (idx <  8192) { W = w1;   N = 128; KB = 2; Kreal = 36;  base = 0; }
  else if (idx < 12288) { W = w2;   N = 32;  KB = 4; Kreal = 128; base = 8192; }
  else if (idx < 24576) { W = wih0; N = 384; KB = 1; Kreal = 32;  base = 12288; }
  else if (idx < 73728) { W = whh0; N = 384; KB = 4; Kreal = 128; base = 24576; }
  else if (idx < 122880){ W = wih1; N = 384; KB = 4; Kreal = 128; base = 73728; }
  else                  { W = whh1; N = 384; KB = 4; Kreal = 128; base = 122880; }
  int li = idx - base;
  int frag = li >> 9;
  int e = li & 511;
  int lane = e >> 3, j = e & 7;
  int kb = frag % KB, nt = frag / KB;
  int k = kb * 32 + (lane >> 4) * 8 + j;
  int n = nt * 16 + (lane & 15);
  float v = (k < Kreal) ? W[k * N + n] : 0.0f;
  ws[base + li] = f2bf(v);
}

// ---------------------------------------------------------------------------
// Kernel 1: Customer MLP. R5: W as A-operand, x/h as B-operand; vectorized
// epilogues (cvt_pk + b64 LDS writes, b64 global stores).
// ---------------------------------------------------------------------------
__global__ __launch_bounds__(256) void mlp_kernel(
    const float* __restrict__ customers, const float* __restrict__ b1,
    const float* __restrict__ b2, const uint16_t* __restrict__ wpk,
    uint16_t* __restrict__ x2out) {
  __shared__ uint16_t sA[128 * 136];
  const int r0 = blockIdx.x * 128;
  const int t  = r0 / NSEQ;
  const int s0 = r0 % NSEQ;
  const int tid = threadIdx.x;
  const int w = tid >> 6, l = tid & 63, q = l >> 4, c = l & 15;
  const int lo8 = l * 8;
  const int hb = 4 * q;                      // this lane's 4 rows within a tile

  floatx4 acc[2][8];
  #pragma unroll
  for (int mi = 0; mi < 2; ++mi)
    #pragma unroll
    for (int nt = 0; nt < 8; ++nt) acc[mi][nt] = (floatx4){0.f, 0.f, 0.f, 0.f};

  #pragma unroll
  for (int mi = 0; mi < 2; ++mi) {
    const int mt = 2 * w + mi;
    const int seq = s0 + mt * 16 + c;
    const float* xp = customers + (size_t)seq * 864 + t * 36;
    floatx4 u0 = *(const floatx4*)(xp + q * 8);
    floatx4 u1 = *(const floatx4*)(xp + q * 8 + 4);
    bf16x8 a0;
    { uint32_t* a0u = (uint32_t*)&a0;
      a0u[0] = cvt_pk(u0[0], u0[1]); a0u[1] = cvt_pk(u0[2], u0[3]);
      a0u[2] = cvt_pk(u1[0], u1[1]); a0u[3] = cvt_pk(u1[2], u1[3]); }
    bf16x8 a1x = (bf16x8){0,0,0,0,0,0,0,0};
    if (q == 0) {
      floatx4 u2 = *(const floatx4*)(xp + 32);
      uint32_t* a1u = (uint32_t*)&a1x;
      a1u[0] = cvt_pk(u2[0], u2[1]); a1u[1] = cvt_pk(u2[2], u2[3]);
    }
    #pragma unroll
    for (int nt = 0; nt < 8; ++nt) {
      bf16x8 bv0 = ldf(wpk + PK_W1 + (nt * 2 + 0) * 512 + lo8);
      bf16x8 bv1 = ldf(wpk + PK_W1 + (nt * 2 + 1) * 512 + lo8);
      MFMA(bv0, a0,  acc[mi][nt]);     // W1 as A, x as B -> D[hid][seq]
      MFMA(bv1, a1x, acc[mi][nt]);
    }
  }
  #pragma unroll
  for (int mi = 0; mi < 2; ++mi) {
    const int mt = 2 * w + mi;
    #pragma unroll
    for (int nt = 0; nt < 8; ++nt) {
      const floatx4 bv = *(const floatx4*)(b1 + nt * 16 + hb);
      float o0 = fast_tanh(acc[mi][nt][0] + bv[0]);
      float o1 = fast_tanh(acc[mi][nt][1] + bv[1]);
      float o2 = fast_tanh(acc[mi][nt][2] + bv[2]);
      float o3 = fast_tanh(acc[mi][nt][3] + bv[3]);
      uint2 pk; pk.x = cvt_pk(o0, o1); pk.y = cvt_pk(o2, o3);
      *(uint2*)&sA[(mt * 16 + c) * 136 + nt * 16 + hb] = pk;  // [seq][hid]
    }
  }
  __syncthreads();

  floatx4 acc2[2][2];
  #pragma unroll
  for (int mi = 0; mi < 2; ++mi)
    #pragma unroll
    for (int nt = 0; nt < 2; ++nt) acc2[mi][nt] = (floatx4){0.f, 0.f, 0.f, 0.f};

  #pragma unroll
  for (int kb = 0; kb < 4; ++kb) {
    bf16x8 av0 = ldf(&sA[((2 * w + 0) * 16 + c) * 136 + kb * 32 + q * 8]);
    bf16x8 av1 = ldf(&sA[((2 * w + 1) * 16 + c) * 136 + kb * 32 + q * 8]);
    #pragma unroll
    for (int nt = 0; nt < 2; ++nt) {
      bf16x8 bv = ldf(wpk + PK_W2 + (nt * 4 + kb) * 512 + lo8);
      MFMA(bv, av0, acc2[0][nt]);      // W2 as A, h as B -> D[out][seq]
      MFMA(bv, av1, acc2[1][nt]);
    }
  }
  #pragma unroll
  for (int mi = 0; mi < 2; ++mi) {
    const int mt = 2 * w + mi;
    #pragma unroll
    for (int nt = 0; nt < 2; ++nt) {
      const floatx4 bv = *(const floatx4*)(b2 + nt * 16 + hb);
      float o0 = fast_tanh(acc2[mi][nt][0] + bv[0]);
      float o1 = fast_tanh(acc2[mi][nt][1] + bv[1]);
      float o2 = fast_tanh(acc2[mi][nt][2] + bv[2]);
      float o3 = fast_tanh(acc2[mi][nt][3] + bv[3]);
      uint2 pk; pk.x = cvt_pk(o0, o1); pk.y = cvt_pk(o2, o3);
      *(uint2*)(x2out + (size_t)(r0 + mt * 16 + c) * 32 + nt * 16 + hb) = pk;
    }
  }
}

// ---------------------------------------------------------------------------
// Kernel 2 (R5): fused 2-layer GRU, weights register-resident as A-frags,
// 8 waves, wave J owns hidden cols [J*16, J*16+16). 32 seqs/block, grid 768.
// D transposed: lane holds hidden 4q..4q+3 of seq c -> b64 h-writes.
// ---------------------------------------------------------------------------
__global__ __launch_bounds__(512, 2) void gru_res(
    const uint16_t* __restrict__ wpk, const uint16_t* __restrict__ x2,
    const float* __restrict__ bih0, const float* __restrict__ bhh0,
    const float* __restrict__ bih1, const float* __restrict__ bhh1,
    float* __restrict__ hout) {
  __shared__ uint16_t hl[2][2][32 * 136];   // [layer][buf][row*136]
  const int seq0 = blockIdx.x * 32;
  const int tid = threadIdx.x;
  const int J = tid >> 6, l = tid & 63, q = l >> 4, c = l & 15;
  const int lo8 = l * 8;

  { uint32_t* z = (uint32_t*)hl;
    for (int i = tid; i < 8704; i += 512) z[i] = 0u; }

  // ---- this wave's weight fragments (A-operands) into VGPRs (39 frags) ----
  bf16x8 wi0[3], wh0[3][4], wi1[3][4], wh1[3][4];
  #pragma unroll
  for (int g = 0; g < 3; ++g) {
    wi0[g] = ldf(wpk + PK_WIH0 + (g * 8 + J) * 512 + lo8);
    #pragma unroll
    for (int kb = 0; kb < 4; ++kb) {
      wh0[g][kb] = ldf(wpk + PK_WHH0 + ((g * 8 + J) * 4 + kb) * 512 + lo8);
      wi1[g][kb] = ldf(wpk + PK_WIH1 + ((g * 8 + J) * 4 + kb) * 512 + lo8);
      wh1[g][kb] = ldf(wpk + PK_WHH1 + ((g * 8 + J) * 4 + kb) * 512 + lo8);
    }
  }
  const int hb = J * 16 + 4 * q;     // this lane's 4 hidden cols
  const floatx4 vR0 = *(const floatx4*)(bih0 + hb)       + *(const floatx4*)(bhh0 + hb);
  const floatx4 vZ0 = *(const floatx4*)(bih0 + 128 + hb) + *(const floatx4*)(bhh0 + 128 + hb);
  const floatx4 vN0 = *(const floatx4*)(bih0 + 256 + hb);
  const floatx4 vH0 = *(const floatx4*)(bhh0 + 256 + hb);
  const floatx4 vR1 = *(const floatx4*)(bih1 + hb)       + *(const floatx4*)(bhh1 + hb);
  const floatx4 vZ1 = *(const floatx4*)(bih1 + 128 + hb) + *(const floatx4*)(bhh1 + 128 + hb);
  const floatx4 vN1 = *(const floatx4*)(bih1 + 256 + hb);
  const floatx4 vH1 = *(const floatx4*)(bhh1 + 256 + hb);

  floatx4 h0m[2], h1m[2];            // lane-local h state: [seq-tile][hid 4q+e]
  h0m[0] = (floatx4){0.f, 0.f, 0.f, 0.f}; h0m[1] = (floatx4){0.f, 0.f, 0.f, 0.f};
  h1m[0] = (floatx4){0.f, 0.f, 0.f, 0.f}; h1m[1] = (floatx4){0.f, 0.f, 0.f, 0.f};

  bf16x8 axc[2];
  axc[0] = ldf(x2 + (size_t)(seq0 + c) * 32 + q * 8);
  axc[1] = ldf(x2 + (size_t)(seq0 + 16 + c) * 32 + q * 8);
  __syncthreads();

  #pragma unroll 1
  for (int t = 0; t < TSTEPS; ++t) {
    const int cur = t & 1, prv = cur ^ 1;
    const int tn = (t < TSTEPS - 1) ? t + 1 : t;
    bf16x8 axn0 = ldf(x2 + ((size_t)tn * NSEQ + seq0 + c) * 32 + q * 8);
    bf16x8 axn1 = ldf(x2 + ((size_t)tn * NSEQ + seq0 + 16 + c) * 32 + q * 8);

    uint16_t* h0w = hl[0][cur]; const uint16_t* h0r = hl[0][prv];
    uint16_t* h1w = hl[1][cur]; const uint16_t* h1r = hl[1][prv];

    // ---------------- layer 0 ----------------
    {
      floatx4 aR[2], aZ[2], aN[2], aH[2];
      #pragma unroll
      for (int mi = 0; mi < 2; ++mi) {
        aR[mi] = vR0; aZ[mi] = vZ0; aN[mi] = vN0; aH[mi] = vH0;
      }
      #pragma unroll
      for (int kb = 0; kb < 4; ++kb) {
        bf16x8 a0 = ldf(h0r + (c)      * 136 + kb * 32 + q * 8);
        bf16x8 a1 = ldf(h0r + (16 + c) * 136 + kb * 32 + q * 8);
        MFMA(wh0[0][kb], a0, aR[0]); MFMA(wh0[0][kb], a1, aR[1]);
        MFMA(wh0[1][kb], a0, aZ[0]); MFMA(wh0[1][kb], a1, aZ[1]);
        MFMA(wh0[2][kb], a0, aH[0]); MFMA(wh0[2][kb], a1, aH[1]);
      }
      MFMA(wi0[0], axc[0], aR[0]); MFMA(wi0[0], axc[1], aR[1]);
      MFMA(wi0[1], axc[0], aZ[0]); MFMA(wi0[1], axc[1], aZ[1]);
      MFMA(wi0[2], axc[0], aN[0]); MFMA(wi0[2], axc[1], aN[1]);
      #pragma unroll
      for (int mi = 0; mi < 2; ++mi) {
        float o[4];
        #pragma unroll
        for (int e = 0; e < 4; ++e) {
          float r  = fast_sigmoid(aR[mi][e]);
          float zz = fast_sigmoid(aZ[mi][e]);
          float nn = fast_tanh(aN[mi][e] + r * aH[mi][e]);
          o[e] = nn + zz * (h0m[mi][e] - nn);
          h0m[mi][e] = o[e];
        }
        uint2 pk; pk.x = cvt_pk(o[0], o[1]); pk.y = cvt_pk(o[2], o[3]);
        *(uint2*)(h0w + (mi * 16 + c) * 136 + hb) = pk;
      }
    }
    __syncthreads();

    // ---------------- layer 1 ----------------
    {
      floatx4 aR[2], aZ[2], aN[2], aH[2];
      #pragma unroll
      for (int mi = 0; mi < 2; ++mi) {
        aR[mi] = vR1; aZ[mi] = vZ1; aN[mi] = vN1; aH[mi] = vH1;
      }
      #pragma unroll
      for (int kb = 0; kb < 4; ++kb) {
        bf16x8 ai0 = ldf(h0w + (c)      * 136 + kb * 32 + q * 8);
        bf16x8 ai1 = ldf(h0w + (16 + c) * 136 + kb * 32 + q * 8);
        bf16x8 ah0 = ldf(h1r + (c)      * 136 + kb * 32 + q * 8);
        bf16x8 ah1 = ldf(h1r + (16 + c) * 136 + kb * 32 + q * 8);
        MFMA(wi1[0][kb], ai0, aR[0]); MFMA(wi1[0][kb], ai1, aR[1]);
        MFMA(wi1[1][kb], ai0, aZ[0]); MFMA(wi1[1][kb], ai1, aZ[1]);
        MFMA(wi1[2][kb], ai0, aN[0]); MFMA(wi1[2][kb], ai1, aN[1]);
        MFMA(wh1[0][kb], ah0, aR[0]); MFMA(wh1[0][kb], ah1, aR[1]);
        MFMA(wh1[1][kb], ah0, aZ[0]); MFMA(wh1[1][kb], ah1, aZ[1]);
        MFMA(wh1[2][kb], ah0, aH[0]); MFMA(wh1[2][kb], ah1, aH[1]);
      }
      #pragma unroll
      for (int mi = 0; mi < 2; ++mi) {
        float o[4];
        #pragma unroll
        for (int e = 0; e < 4; ++e) {
          float r  = fast_sigmoid(aR[mi][e]);
          float zz = fast_sigmoid(aZ[mi][e]);
          float nn = fast_tanh(aN[mi][e] + r * aH[mi][e]);
          o[e] = nn + zz * (h1m[mi][e] - nn);
          h1m[mi][e] = o[e];
        }
        uint2 pk; pk.x = cvt_pk(o[0], o[1]); pk.y = cvt_pk(o[2], o[3]);
        *(uint2*)(h1w + (mi * 16 + c) * 136 + hb) = pk;
      }
    }
    __syncthreads();
    axc[0] = axn0; axc[1] = axn1;
  }

  #pragma unroll
  for (int mi = 0; mi < 2; ++mi)
    *(floatx4*)(hout + (size_t)(seq0 + mi * 16 + c) * 128 + hb) = h1m[mi];
}

// ---------------------------------------------------------------------------
// Kernel 3: mean over routes + candidate head + fc1/fc2/fc3 (unchanged)
// ---------------------------------------------------------------------------
__global__ __launch_bounds__(192) void final_kernel(
    const float* __restrict__ hout, const float* __restrict__ cands,
    const float* __restrict__ cw, const float* __restrict__ cb,
    const float* __restrict__ f1w, const float* __restrict__ f1b,
    const float* __restrict__ f2w, const float* __restrict__ f2b,
    const float* __restrict__ f3w, const float* __restrict__ f3b,
    float* __restrict__ out) {
  __shared__ float hc[192];
  __shared__ float v1[128];
  __shared__ float v2[128];
  __shared__ float red[128];
  const int b = blockIdx.x, tid = threadIdx.x;
  if (tid < 128) {
    float s = 0.f;
    const float* hp = hout + (size_t)(b * 48) * 128 + tid;
    #pragma unroll 4
    for (int r = 0; r < 48; ++r) s += hp[r * 128];
    hc[tid] = s * (1.0f / 48.0f);
  } else {
    int j = tid - 128;
    float s = cb[j];
    const float* cp = cands + b * 72;
    #pragma unroll 8
    for (int k = 0; k < 72; ++k) s += cp[k] * cw[k * 64 + j];
    hc[128 + j] = s;
  }
  __syncthreads();
  if (tid < 128) {
    float s = f1b[tid];
    for (int k = 0; k < 192; ++k) s += hc[k] * f1w[k * 128 + tid];
    v1[tid] = fast_tanh(s);
  }
  __syncthreads();
  if (tid < 128) {
    float s = f2b[tid];
    for (int k = 0; k < 128; ++k) s += v1[k] * f2w[k * 128 + tid];
    v2[tid] = fast_tanh(s);
  }
  __syncthreads();
  if (tid < 128) red[tid] = v2[tid] * f3w[tid];
  __syncthreads();
  if (tid < 64) {
    float s = red[tid] + red[tid + 64];
    s += __shfl_down(s, 32);
    s += __shfl_down(s, 16);
    s += __shfl_down(s, 8);
    s += __shfl_down(s, 4);
    s += __shfl_down(s, 2);
    s += __shfl_down(s, 1);
    if (tid == 0) out[b] = s + f3b[0];
  }
}

// ---------------------------------------------------------------------------
extern "C" void kernel_launch(void* const* d_in, const int* in_sizes, int n_in,
                              void* d_out, int out_size, void* d_ws, size_t ws_size,
                              hipStream_t stream) {
  const float* cand  = (const float*)d_in[0];
  const float* cust  = (const float*)d_in[1];
  const float* w1    = (const float*)d_in[2];
  const float* b1    = (const float*)d_in[3];
  const float* w2    = (const float*)d_in[4];
  const float* b2    = (const float*)d_in[5];
  const float* wih0  = (const float*)d_in[6];
  const float* whh0  = (const float*)d_in[7];
  const float* bih0  = (const float*)d_in[8];
  const float* bhh0  = (const float*)d_in[9];
  const float* wih1  = (const float*)d_in[10];
  const float* whh1  = (const float*)d_in[11];
  const float* bih1  = (const float*)d_in[12];
  const float* bhh1  = (const float*)d_in[13];
  const float* cw    = (const float*)d_in[14];
  const float* cb    = (const float*)d_in[15];
  const float* f1w   = (const float*)d_in[16];
  const float* f1b   = (const float*)d_in[17];
  const float* f2w   = (const float*)d_in[18];
  const float* f2b   = (const float*)d_in[19];
  const float* f3w   = (const float*)d_in[20];
  const float* f3b   = (const float*)d_in[21];

  uint16_t* wsp = (uint16_t*)d_ws;
  uint16_t* x2p = wsp + X2_EL;
  float* hout = (float*)((char*)d_ws + HOUT_BYTE);
  float* outp = (float*)d_out;

  pack_weights<<<(PK_END + 255) / 256, 256, 0, stream>>>(w1, w2, wih0, whh0, wih1, whh1, wsp);
  mlp_kernel<<<(NSEQ * TSTEPS) / 128, 256, 0, stream>>>(cust, b1, b2, wsp, x2p);
  gru_res<<<NSEQ / 32, 512, 0, stream>>>(wsp, x2p, bih0, bhh0, bih1, bhh1, hout);
  final_kernel<<<512, 192, 0, stream>>>(hout, cand, cw, cb, f1w, f1b, f2w, f2b, f3w, f3b, outp);
}

// Round 3
// 419.991 us; speedup vs baseline: 1.0481x; 1.0481x over previous
//
#include <hip/hip_runtime.h>
#include <stdint.h>

// ---------------------------------------------------------------------------
// MLP_Model: candidates head + per-route Customer MLP + 2-layer GRU + FC head
// R6: gru_res restructured to a SINGLE-BARRIER software-pipelined step:
// phase t computes {L1[t], L0[t+1]} together (both depend only on h0[t]),
// giving each wave two independent MFMA+transcendental chains to interleave
// and halving barrier count (24 vs 48). Seqs/block halved to 16 (grid 1536)
// and biases moved to LDS so the merged accumulators fit ~<=240 regs/wave
// without spill. h0[t] fragments are shared by L1-input and L0-recurrence
// (8 ds_reads/phase instead of 16). mlp/final unchanged from R5.
// ws layout: [0,344064) packed bf16 weights; [344064,38092800) x2 bf16;
// [38092800,...) h1 final fp32 (~50.7 MB total).
// ---------------------------------------------------------------------------

#define NSEQ   24576   // 512 * 48
#define TSTEPS 24
#define SEQB   16      // sequences per gru block (R6: was 32)

typedef __attribute__((ext_vector_type(8))) short bf16x8;
typedef __attribute__((ext_vector_type(4))) float floatx4;

// packed-weight element offsets (uint16 units)
#define PK_W1    0
#define PK_W2    8192
#define PK_WIH0  12288
#define PK_WHH0  24576
#define PK_WIH1  73728
#define PK_WHH1  122880
#define PK_END   172032
#define X2_EL    172032                 // x2: [t][seq][32] bf16
#define HOUT_BYTE 38092800              // h1 final: [seq][128] fp32

#define MFMA(a,b,c) c = __builtin_amdgcn_mfma_f32_16x16x32_bf16(a, b, c, 0, 0, 0)

__device__ __forceinline__ uint16_t f2bf(float f) {
  uint32_t u = __float_as_uint(f);
  u += 0x7FFFu + ((u >> 16) & 1u);           // RNE
  return (uint16_t)(u >> 16);
}
// packed f32x2 -> bf16x2 (RNE), single VALU op. lo half = first arg.
__device__ __forceinline__ uint32_t cvt_pk(float a, float b) {
  uint32_t r;
  asm("v_cvt_pk_bf16_f32 %0, %1, %2" : "=v"(r) : "v"(a), "v"(b));
  return r;
}
__device__ __forceinline__ float fast_sigmoid(float x) {
  float e = __builtin_amdgcn_exp2f(-1.4426950408889634f * x);
  return __builtin_amdgcn_rcpf(1.0f + e);
}
__device__ __forceinline__ float fast_tanh(float x) {
  float e = __builtin_amdgcn_exp2f(-2.8853900817779268f * x);
  return 2.0f * __builtin_amdgcn_rcpf(1.0f + e) - 1.0f;
}
__device__ __forceinline__ bf16x8 ldf(const uint16_t* p) {
  return *(const bf16x8*)p;
}

// ---------------------------------------------------------------------------
// Kernel 0: pack all weights to bf16 fragment layout. (unchanged — the
// layout is simultaneously a valid B-frag (n=lane&15) and A-frag (m=lane&15))
// ---------------------------------------------------------------------------
__global__ __launch_bounds__(256) void pack_weights(
    const float* __restrict__ w1, const float* __restrict__ w2,
    const float* __restrict__ wih0, const float* __restrict__ whh0,
    const float* __restrict__ wih1, const float* __restrict__ whh1,
    uint16_t* __restrict__ ws) {
  int idx = blockIdx.x * 256 + threadIdx.x;
  if (idx >= PK_END) return;
  const float* W; int N, KB, Kreal, base;
  if      (idx <  8192) { W = w1;   N = 128; KB = 2; Kreal = 36;  base = 0; }
  else if (idx < 12288) { W = w2;   N = 32;  KB = 4; Kreal = 128; base = 8192; }
  else if (idx < 24576) { W = wih0; N = 384; KB = 1; Kreal = 32;  base = 12288; }
  else if (idx < 73728) { W = whh0; N = 384; KB = 4; Kreal = 128; base = 24576; }
  else if (idx < 122880){ W = wih1; N = 384; KB = 4; Kreal = 128; base = 73728; }
  else                  { W = whh1; N = 384; KB = 4; Kreal = 128; base = 122880; }
  int li = idx - base;
  int frag = li >> 9;
  int e = li & 511;
  int lane = e >> 3, j = e & 7;
  int kb = frag % KB, nt = frag / KB;
  int k = kb * 32 + (lane >> 4) * 8 + j;
  int n = nt * 16 + (lane & 15);
  float v = (k < Kreal) ? W[k * N + n] : 0.0f;
  ws[base + li] = f2bf(v);
}

// ---------------------------------------------------------------------------
// Kernel 1: Customer MLP (unchanged from R5).
// ---------------------------------------------------------------------------
__global__ __launch_bounds__(256) void mlp_kernel(
    const float* __restrict__ customers, const float* __restrict__ b1,
    const float* __restrict__ b2, const uint16_t* __restrict__ wpk,
    uint16_t* __restrict__ x2out) {
  __shared__ uint16_t sA[128 * 136];
  const int r0 = blockIdx.x * 128;
  const int t  = r0 / NSEQ;
  const int s0 = r0 % NSEQ;
  const int tid = threadIdx.x;
  const int w = tid >> 6, l = tid & 63, q = l >> 4, c = l & 15;
  const int lo8 = l * 8;
  const int hb = 4 * q;                      // this lane's 4 rows within a tile

  floatx4 acc[2][8];
  #pragma unroll
  for (int mi = 0; mi < 2; ++mi)
    #pragma unroll
    for (int nt = 0; nt < 8; ++nt) acc[mi][nt] = (floatx4){0.f, 0.f, 0.f, 0.f};

  #pragma unroll
  for (int mi = 0; mi < 2; ++mi) {
    const int mt = 2 * w + mi;
    const int seq = s0 + mt * 16 + c;
    const float* xp = customers + (size_t)seq * 864 + t * 36;
    floatx4 u0 = *(const floatx4*)(xp + q * 8);
    floatx4 u1 = *(const floatx4*)(xp + q * 8 + 4);
    bf16x8 a0;
    { uint32_t* a0u = (uint32_t*)&a0;
      a0u[0] = cvt_pk(u0[0], u0[1]); a0u[1] = cvt_pk(u0[2], u0[3]);
      a0u[2] = cvt_pk(u1[0], u1[1]); a0u[3] = cvt_pk(u1[2], u1[3]); }
    bf16x8 a1x = (bf16x8){0,0,0,0,0,0,0,0};
    if (q == 0) {
      floatx4 u2 = *(const floatx4*)(xp + 32);
      uint32_t* a1u = (uint32_t*)&a1x;
      a1u[0] = cvt_pk(u2[0], u2[1]); a1u[1] = cvt_pk(u2[2], u2[3]);
    }
    #pragma unroll
    for (int nt = 0; nt < 8; ++nt) {
      bf16x8 bv0 = ldf(wpk + PK_W1 + (nt * 2 + 0) * 512 + lo8);
      bf16x8 bv1 = ldf(wpk + PK_W1 + (nt * 2 + 1) * 512 + lo8);
      MFMA(bv0, a0,  acc[mi][nt]);     // W1 as A, x as B -> D[hid][seq]
      MFMA(bv1, a1x, acc[mi][nt]);
    }
  }
  #pragma unroll
  for (int mi = 0; mi < 2; ++mi) {
    const int mt = 2 * w + mi;
    #pragma unroll
    for (int nt = 0; nt < 8; ++nt) {
      const floatx4 bv = *(const floatx4*)(b1 + nt * 16 + hb);
      float o0 = fast_tanh(acc[mi][nt][0] + bv[0]);
      float o1 = fast_tanh(acc[mi][nt][1] + bv[1]);
      float o2 = fast_tanh(acc[mi][nt][2] + bv[2]);
      float o3 = fast_tanh(acc[mi][nt][3] + bv[3]);
      uint2 pk; pk.x = cvt_pk(o0, o1); pk.y = cvt_pk(o2, o3);
      *(uint2*)&sA[(mt * 16 + c) * 136 + nt * 16 + hb] = pk;  // [seq][hid]
    }
  }
  __syncthreads();

  floatx4 acc2[2][2];
  #pragma unroll
  for (int mi = 0; mi < 2; ++mi)
    #pragma unroll
    for (int nt = 0; nt < 2; ++nt) acc2[mi][nt] = (floatx4){0.f, 0.f, 0.f, 0.f};

  #pragma unroll
  for (int kb = 0; kb < 4; ++kb) {
    bf16x8 av0 = ldf(&sA[((2 * w + 0) * 16 + c) * 136 + kb * 32 + q * 8]);
    bf16x8 av1 = ldf(&sA[((2 * w + 1) * 16 + c) * 136 + kb * 32 + q * 8]);
    #pragma unroll
    for (int nt = 0; nt < 2; ++nt) {
      bf16x8 bv = ldf(wpk + PK_W2 + (nt * 4 + kb) * 512 + lo8);
      MFMA(bv, av0, acc2[0][nt]);      // W2 as A, h as B -> D[out][seq]
      MFMA(bv, av1, acc2[1][nt]);
    }
  }
  #pragma unroll
  for (int mi = 0; mi < 2; ++mi) {
    const int mt = 2 * w + mi;
    #pragma unroll
    for (int nt = 0; nt < 2; ++nt) {
      const floatx4 bv = *(const floatx4*)(b2 + nt * 16 + hb);
      float o0 = fast_tanh(acc2[mi][nt][0] + bv[0]);
      float o1 = fast_tanh(acc2[mi][nt][1] + bv[1]);
      float o2 = fast_tanh(acc2[mi][nt][2] + bv[2]);
      float o3 = fast_tanh(acc2[mi][nt][3] + bv[3]);
      uint2 pk; pk.x = cvt_pk(o0, o1); pk.y = cvt_pk(o2, o3);
      *(uint2*)(x2out + (size_t)(r0 + mt * 16 + c) * 32 + nt * 16 + hb) = pk;
    }
  }
}

// ---------------------------------------------------------------------------
// Kernel 2 (R6): fused 2-layer GRU, single barrier per timestep.
// Phase t computes {L1[t], L0[t+1]} — both read only h0[t] (+ h1[t-1] /
// x[t+1]), so one __syncthreads per phase suffices and the two layers'
// MFMA+trans chains interleave. 16 seqs/block, grid 1536, 8 waves,
// wave J owns hidden cols [J*16, J*16+16). Biases live in LDS.
// ---------------------------------------------------------------------------
__global__ __launch_bounds__(512, 2) void gru_res(
    const uint16_t* __restrict__ wpk, const uint16_t* __restrict__ x2,
    const float* __restrict__ bih0, const float* __restrict__ bhh0,
    const float* __restrict__ bih1, const float* __restrict__ bhh1,
    float* __restrict__ hout) {
  __shared__ uint16_t h0l[2][SEQB * 136];   // h0[t] double buffer
  __shared__ uint16_t h1l[2][SEQB * 136];   // h1[t] double buffer
  __shared__ float bias_l[8][128];          // R0,Z0,N0,H0,R1,Z1,N1,H1
  const int seq0 = blockIdx.x * SEQB;
  const int tid = threadIdx.x;
  const int J = tid >> 6, l = tid & 63, q = l >> 4, c = l & 15;
  const int lo8 = l * 8;

  // zero h1[-1]
  for (int i = tid; i < 1088; i += 512) ((uint32_t*)h1l[0])[i] = 0u;
  // bias table: [0]=bih0+bhh0 r, [1]=.. z, [2]=bih0 n, [3]=bhh0 n, [4..7]=layer1
  for (int i = tid; i < 1024; i += 512) {
    int g = i >> 7, k = i & 127;
    float v;
    if      (g == 0) v = bih0[k]       + bhh0[k];
    else if (g == 1) v = bih0[128 + k] + bhh0[128 + k];
    else if (g == 2) v = bih0[256 + k];
    else if (g == 3) v = bhh0[256 + k];
    else if (g == 4) v = bih1[k]       + bhh1[k];
    else if (g == 5) v = bih1[128 + k] + bhh1[128 + k];
    else if (g == 6) v = bih1[256 + k];
    else             v = bhh1[256 + k];
    bias_l[g][k] = v;
  }

  // ---- this wave's weight fragments (A-operands) into VGPRs (39 frags) ----
  bf16x8 wi0[3], wh0[3][4], wi1[3][4], wh1[3][4];
  #pragma unroll
  for (int g = 0; g < 3; ++g) {
    wi0[g] = ldf(wpk + PK_WIH0 + (g * 8 + J) * 512 + lo8);
    #pragma unroll
    for (int kb = 0; kb < 4; ++kb) {
      wh0[g][kb] = ldf(wpk + PK_WHH0 + ((g * 8 + J) * 4 + kb) * 512 + lo8);
      wi1[g][kb] = ldf(wpk + PK_WIH1 + ((g * 8 + J) * 4 + kb) * 512 + lo8);
      wh1[g][kb] = ldf(wpk + PK_WHH1 + ((g * 8 + J) * 4 + kb) * 512 + lo8);
    }
  }
  const int hb = J * 16 + 4 * q;     // this lane's 4 hidden cols (& bias idx)

  floatx4 h0m, h1m = (floatx4){0.f, 0.f, 0.f, 0.f};

  bf16x8 ax0 = ldf(x2 + (size_t)(seq0 + c) * 32 + q * 8);            // x[0]
  bf16x8 ax  = ldf(x2 + ((size_t)NSEQ + seq0 + c) * 32 + q * 8);     // x[1]
  __syncthreads();   // bias_l + zeroed h1l[0] visible

  // ---- prologue: L0[0] with h0[-1]=0 (skip Whh MFMAs) -> h0l[0] ----
  {
    floatx4 aR = *(const floatx4*)&bias_l[0][hb];
    floatx4 aZ = *(const floatx4*)&bias_l[1][hb];
    floatx4 aN = *(const floatx4*)&bias_l[2][hb];
    floatx4 aH = *(const floatx4*)&bias_l[3][hb];
    MFMA(wi0[0], ax0, aR); MFMA(wi0[1], ax0, aZ); MFMA(wi0[2], ax0, aN);
    float o[4];
    #pragma unroll
    for (int e = 0; e < 4; ++e) {
      float r  = fast_sigmoid(aR[e]);
      float zz = fast_sigmoid(aZ[e]);
      float nn = fast_tanh(aN[e] + r * aH[e]);
      o[e] = nn - zz * nn;               // h_prev = 0
      h0m[e] = o[e];
    }
    uint2 pk; pk.x = cvt_pk(o[0], o[1]); pk.y = cvt_pk(o[2], o[3]);
    *(uint2*)(h0l[0] + c * 136 + hb) = pk;
  }
  __syncthreads();

  // ---- main: phase t = {L1[t], L0[t+1]}, ONE barrier per phase ----
  #pragma unroll 1
  for (int t = 0; t < TSTEPS; ++t) {
    const uint16_t* h0cur = h0l[t & 1];          // h0[t]
    const uint16_t* h1prv = h1l[t & 1];          // h1[t-1]
    uint16_t* h0nxt = h0l[(t + 1) & 1];          // h0[t+1]
    uint16_t* h1cur = h1l[(t + 1) & 1];          // h1[t]
    const int tnx = (t + 2 < TSTEPS) ? t + 2 : TSTEPS - 1;
    bf16x8 axn = ldf(x2 + ((size_t)tnx * NSEQ + seq0 + c) * 32 + q * 8);

    floatx4 aR1 = *(const floatx4*)&bias_l[4][hb];
    floatx4 aZ1 = *(const floatx4*)&bias_l[5][hb];
    floatx4 aN1 = *(const floatx4*)&bias_l[6][hb];
    floatx4 aH1 = *(const floatx4*)&bias_l[7][hb];
    floatx4 aR0 = *(const floatx4*)&bias_l[0][hb];
    floatx4 aZ0 = *(const floatx4*)&bias_l[1][hb];
    floatx4 aN0 = *(const floatx4*)&bias_l[2][hb];
    floatx4 aH0 = *(const floatx4*)&bias_l[3][hb];

    #pragma unroll
    for (int kb = 0; kb < 4; ++kb) {
      bf16x8 a0 = ldf(h0cur + c * 136 + kb * 32 + q * 8);  // shared: L1-in & L0-rec
      bf16x8 ah = ldf(h1prv + c * 136 + kb * 32 + q * 8);
      MFMA(wi1[0][kb], a0, aR1); MFMA(wh1[0][kb], ah, aR1);
      MFMA(wi1[1][kb], a0, aZ1); MFMA(wh1[1][kb], ah, aZ1);
      MFMA(wi1[2][kb], a0, aN1); MFMA(wh1[2][kb], ah, aH1);
      MFMA(wh0[0][kb], a0, aR0);
      MFMA(wh0[1][kb], a0, aZ0);
      MFMA(wh0[2][kb], a0, aH0);
    }
    MFMA(wi0[0], ax, aR0); MFMA(wi0[1], ax, aZ0); MFMA(wi0[2], ax, aN0);

    // L1 epilogue -> h1[t]
    {
      float o[4];
      #pragma unroll
      for (int e = 0; e < 4; ++e) {
        float r  = fast_sigmoid(aR1[e]);
        float zz = fast_sigmoid(aZ1[e]);
        float nn = fast_tanh(aN1[e] + r * aH1[e]);
        o[e] = nn + zz * (h1m[e] - nn);
        h1m[e] = o[e];
      }
      uint2 pk; pk.x = cvt_pk(o[0], o[1]); pk.y = cvt_pk(o[2], o[3]);
      *(uint2*)(h1cur + c * 136 + hb) = pk;
    }
    // L0 epilogue -> h0[t+1]  (t==23 iteration is dead work; buffers disjoint)
    {
      float o[4];
      #pragma unroll
      for (int e = 0; e < 4; ++e) {
        float r  = fast_sigmoid(aR0[e]);
        float zz = fast_sigmoid(aZ0[e]);
        float nn = fast_tanh(aN0[e] + r * aH0[e]);
        o[e] = nn + zz * (h0m[e] - nn);
        h0m[e] = o[e];
      }
      uint2 pk; pk.x = cvt_pk(o[0], o[1]); pk.y = cvt_pk(o[2], o[3]);
      *(uint2*)(h0nxt + c * 136 + hb) = pk;
    }
    __syncthreads();
    ax = axn;
  }

  *(floatx4*)(hout + (size_t)(seq0 + c) * 128 + hb) = h1m;
}

// ---------------------------------------------------------------------------
// Kernel 3: mean over routes + candidate head + fc1/fc2/fc3 (unchanged)
// ---------------------------------------------------------------------------
__global__ __launch_bounds__(192) void final_kernel(
    const float* __restrict__ hout, const float* __restrict__ cands,
    const float* __restrict__ cw, const float* __restrict__ cb,
    const float* __restrict__ f1w, const float* __restrict__ f1b,
    const float* __restrict__ f2w, const float* __restrict__ f2b,
    const float* __restrict__ f3w, const float* __restrict__ f3b,
    float* __restrict__ out) {
  __shared__ float hc[192];
  __shared__ float v1[128];
  __shared__ float v2[128];
  __shared__ float red[128];
  const int b = blockIdx.x, tid = threadIdx.x;
  if (tid < 128) {
    float s = 0.f;
    const float* hp = hout + (size_t)(b * 48) * 128 + tid;
    #pragma unroll 4
    for (int r = 0; r < 48; ++r) s += hp[r * 128];
    hc[tid] = s * (1.0f / 48.0f);
  } else {
    int j = tid - 128;
    float s = cb[j];
    const float* cp = cands + b * 72;
    #pragma unroll 8
    for (int k = 0; k < 72; ++k) s += cp[k] * cw[k * 64 + j];
    hc[128 + j] = s;
  }
  __syncthreads();
  if (tid < 128) {
    float s = f1b[tid];
    for (int k = 0; k < 192; ++k) s += hc[k] * f1w[k * 128 + tid];
    v1[tid] = fast_tanh(s);
  }
  __syncthreads();
  if (tid < 128) {
    float s = f2b[tid];
    for (int k = 0; k < 128; ++k) s += v1[k] * f2w[k * 128 + tid];
    v2[tid] = fast_tanh(s);
  }
  __syncthreads();
  if (tid < 128) red[tid] = v2[tid] * f3w[tid];
  __syncthreads();
  if (tid < 64) {
    float s = red[tid] + red[tid + 64];
    s += __shfl_down(s, 32);
    s += __shfl_down(s, 16);
    s += __shfl_down(s, 8);
    s += __shfl_down(s, 4);
    s += __shfl_down(s, 2);
    s += __shfl_down(s, 1);
    if (tid == 0) out[b] = s + f3b[0];
  }
}

// ---------------------------------------------------------------------------
extern "C" void kernel_launch(void* const* d_in, const int* in_sizes, int n_in,
                              void* d_out, int out_size, void* d_ws, size_t ws_size,
                              hipStream_t stream) {
  const float* cand  = (const float*)d_in[0];
  const float* cust  = (const float*)d_in[1];
  const float* w1    = (const float*)d_in[2];
  const float* b1    = (const float*)d_in[3];
  const float* w2    = (const float*)d_in[4];
  const float* b2    = (const float*)d_in[5];
  const float* wih0  = (const float*)d_in[6];
  const float* whh0  = (const float*)d_in[7];
  const float* bih0  = (const float*)d_in[8];
  const float* bhh0  = (const float*)d_in[9];
  const float* wih1  = (const float*)d_in[10];
  const float* whh1  = (const float*)d_in[11];
  const float* bih1  = (const float*)d_in[12];
  const float* bhh1  = (const float*)d_in[13];
  const float* cw    = (const float*)d_in[14];
  const float* cb    = (const float*)d_in[15];
  const float* f1w   = (const float*)d_in[16];
  const float* f1b   = (const float*)d_in[17];
  const float* f2w   = (const float*)d_in[18];
  const float* f2b   = (const float*)d_in[19];
  const float* f3w   = (const float*)d_in[20];
  const float* f3b   = (const float*)d_in[21];

  uint16_t* wsp = (uint16_t*)d_ws;
  uint16_t* x2p = wsp + X2_EL;
  float* hout = (float*)((char*)d_ws + HOUT_BYTE);
  float* outp = (float*)d_out;

  pack_weights<<<(PK_END + 255) / 256, 256, 0, stream>>>(w1, w2, wih0, whh0, wih1, whh1, wsp);
  mlp_kernel<<<(NSEQ * TSTEPS) / 128, 256, 0, stream>>>(cust, b1, b2, wsp, x2p);
  gru_res<<<NSEQ / SEQB, 512, 0, stream>>>(wsp, x2p, bih0, bhh0, bih1, bhh1, hout);
  final_kernel<<<512, 192, 0, stream>>>(hout, cand, cw, cb, f1w, f1b, f2w, f2b, f3w, f3b, outp);
}

// Round 4
// 411.733 us; speedup vs baseline: 1.0692x; 1.0201x over previous
//
#include <hip/hip_runtime.h>
#include <stdint.h>

// ---------------------------------------------------------------------------
// MLP_Model: candidates head + per-route Customer MLP + 2-layer GRU + FC head
// R7: gru_res keeps R6's merged single-barrier phase {L1[t], L0[t+1]} but
// doubles seqs/block back to 32 (grid 768 -> 3 sequential rounds instead of
// 6). The two 16-seq tiles are processed SEQUENTIALLY within a phase with
// REUSED accumulator registers (sched_barrier(0) between tiles pins the
// live-range split), so reg footprint stays ~245/wave (2 waves/SIMD, no
// spill) while per-phase fixed costs (barrier drain, bubbles) amortize over
// 2x work. Per-tile persistent state explicitly named (no runtime indexing).
// mlp/final/pack unchanged.
// ws layout: [0,344064) packed bf16 weights; [344064,38092800) x2 bf16;
// [38092800,...) h1 final fp32 (~50.7 MB total).
// ---------------------------------------------------------------------------

#define NSEQ   24576   // 512 * 48
#define TSTEPS 24
#define SEQB   32      // sequences per gru block (R7: back to 32, 2 tiles)

typedef __attribute__((ext_vector_type(8))) short bf16x8;
typedef __attribute__((ext_vector_type(4))) float floatx4;

// packed-weight element offsets (uint16 units)
#define PK_W1    0
#define PK_W2    8192
#define PK_WIH0  12288
#define PK_WHH0  24576
#define PK_WIH1  73728
#define PK_WHH1  122880
#define PK_END   172032
#define X2_EL    172032                 // x2: [t][seq][32] bf16
#define HOUT_BYTE 38092800              // h1 final: [seq][128] fp32

#define MFMA(a,b,c) c = __builtin_amdgcn_mfma_f32_16x16x32_bf16(a, b, c, 0, 0, 0)

__device__ __forceinline__ uint16_t f2bf(float f) {
  uint32_t u = __float_as_uint(f);
  u += 0x7FFFu + ((u >> 16) & 1u);           // RNE
  return (uint16_t)(u >> 16);
}
// packed f32x2 -> bf16x2 (RNE), single VALU op. lo half = first arg.
__device__ __forceinline__ uint32_t cvt_pk(float a, float b) {
  uint32_t r;
  asm("v_cvt_pk_bf16_f32 %0, %1, %2" : "=v"(r) : "v"(a), "v"(b));
  return r;
}
__device__ __forceinline__ float fast_sigmoid(float x) {
  float e = __builtin_amdgcn_exp2f(-1.4426950408889634f * x);
  return __builtin_amdgcn_rcpf(1.0f + e);
}
__device__ __forceinline__ float fast_tanh(float x) {
  float e = __builtin_amdgcn_exp2f(-2.8853900817779268f * x);
  return 2.0f * __builtin_amdgcn_rcpf(1.0f + e) - 1.0f;
}
__device__ __forceinline__ bf16x8 ldf(const uint16_t* p) {
  return *(const bf16x8*)p;
}

// ---------------------------------------------------------------------------
// Kernel 0: pack all weights to bf16 fragment layout. (unchanged — the
// layout is simultaneously a valid B-frag (n=lane&15) and A-frag (m=lane&15))
// ---------------------------------------------------------------------------
__global__ __launch_bounds__(256) void pack_weights(
    const float* __restrict__ w1, const float* __restrict__ w2,
    const float* __restrict__ wih0, const float* __restrict__ whh0,
    const float* __restrict__ wih1, const float* __restrict__ whh1,
    uint16_t* __restrict__ ws) {
  int idx = blockIdx.x * 256 + threadIdx.x;
  if (idx >= PK_END) return;
  const float* W; int N, KB, Kreal, base;
  if      (idx <  8192) { W = w1;   N = 128; KB = 2; Kreal = 36;  base = 0; }
  else if (idx < 12288) { W = w2;   N = 32;  KB = 4; Kreal = 128; base = 8192; }
  else if (idx < 24576) { W = wih0; N = 384; KB = 1; Kreal = 32;  base = 12288; }
  else if (idx < 73728) { W = whh0; N = 384; KB = 4; Kreal = 128; base = 24576; }
  else if (idx < 122880){ W = wih1; N = 384; KB = 4; Kreal = 128; base = 73728; }
  else                  { W = whh1; N = 384; KB = 4; Kreal = 128; base = 122880; }
  int li = idx - base;
  int frag = li >> 9;
  int e = li & 511;
  int lane = e >> 3, j = e & 7;
  int kb = frag % KB, nt = frag / KB;
  int k = kb * 32 + (lane >> 4) * 8 + j;
  int n = nt * 16 + (lane & 15);
  float v = (k < Kreal) ? W[k * N + n] : 0.0f;
  ws[base + li] = f2bf(v);
}

// ---------------------------------------------------------------------------
// Kernel 1: Customer MLP (unchanged from R5).
// ---------------------------------------------------------------------------
__global__ __launch_bounds__(256) void mlp_kernel(
    const float* __restrict__ customers, const float* __restrict__ b1,
    const float* __restrict__ b2, const uint16_t* __restrict__ wpk,
    uint16_t* __restrict__ x2out) {
  __shared__ uint16_t sA[128 * 136];
  const int r0 = blockIdx.x * 128;
  const int t  = r0 / NSEQ;
  const int s0 = r0 % NSEQ;
  const int tid = threadIdx.x;
  const int w = tid >> 6, l = tid & 63, q = l >> 4, c = l & 15;
  const int lo8 = l * 8;
  const int hb = 4 * q;                      // this lane's 4 rows within a tile

  floatx4 acc[2][8];
  #pragma unroll
  for (int mi = 0; mi < 2; ++mi)
    #pragma unroll
    for (int nt = 0; nt < 8; ++nt) acc[mi][nt] = (floatx4){0.f, 0.f, 0.f, 0.f};

  #pragma unroll
  for (int mi = 0; mi < 2; ++mi) {
    const int mt = 2 * w + mi;
    const int seq = s0 + mt * 16 + c;
    const float* xp = customers + (size_t)seq * 864 + t * 36;
    floatx4 u0 = *(const floatx4*)(xp + q * 8);
    floatx4 u1 = *(const floatx4*)(xp + q * 8 + 4);
    bf16x8 a0;
    { uint32_t* a0u = (uint32_t*)&a0;
      a0u[0] = cvt_pk(u0[0], u0[1]); a0u[1] = cvt_pk(u0[2], u0[3]);
      a0u[2] = cvt_pk(u1[0], u1[1]); a0u[3] = cvt_pk(u1[2], u1[3]); }
    bf16x8 a1x = (bf16x8){0,0,0,0,0,0,0,0};
    if (q == 0) {
      floatx4 u2 = *(const floatx4*)(xp + 32);
      uint32_t* a1u = (uint32_t*)&a1x;
      a1u[0] = cvt_pk(u2[0], u2[1]); a1u[1] = cvt_pk(u2[2], u2[3]);
    }
    #pragma unroll
    for (int nt = 0; nt < 8; ++nt) {
      bf16x8 bv0 = ldf(wpk + PK_W1 + (nt * 2 + 0) * 512 + lo8);
      bf16x8 bv1 = ldf(wpk + PK_W1 + (nt * 2 + 1) * 512 + lo8);
      MFMA(bv0, a0,  acc[mi][nt]);     // W1 as A, x as B -> D[hid][seq]
      MFMA(bv1, a1x, acc[mi][nt]);
    }
  }
  #pragma unroll
  for (int mi = 0; mi < 2; ++mi) {
    const int mt = 2 * w + mi;
    #pragma unroll
    for (int nt = 0; nt < 8; ++nt) {
      const floatx4 bv = *(const floatx4*)(b1 + nt * 16 + hb);
      float o0 = fast_tanh(acc[mi][nt][0] + bv[0]);
      float o1 = fast_tanh(acc[mi][nt][1] + bv[1]);
      float o2 = fast_tanh(acc[mi][nt][2] + bv[2]);
      float o3 = fast_tanh(acc[mi][nt][3] + bv[3]);
      uint2 pk; pk.x = cvt_pk(o0, o1); pk.y = cvt_pk(o2, o3);
      *(uint2*)&sA[(mt * 16 + c) * 136 + nt * 16 + hb] = pk;  // [seq][hid]
    }
  }
  __syncthreads();

  floatx4 acc2[2][2];
  #pragma unroll
  for (int mi = 0; mi < 2; ++mi)
    #pragma unroll
    for (int nt = 0; nt < 2; ++nt) acc2[mi][nt] = (floatx4){0.f, 0.f, 0.f, 0.f};

  #pragma unroll
  for (int kb = 0; kb < 4; ++kb) {
    bf16x8 av0 = ldf(&sA[((2 * w + 0) * 16 + c) * 136 + kb * 32 + q * 8]);
    bf16x8 av1 = ldf(&sA[((2 * w + 1) * 16 + c) * 136 + kb * 32 + q * 8]);
    #pragma unroll
    for (int nt = 0; nt < 2; ++nt) {
      bf16x8 bv = ldf(wpk + PK_W2 + (nt * 4 + kb) * 512 + lo8);
      MFMA(bv, av0, acc2[0][nt]);      // W2 as A, h as B -> D[out][seq]
      MFMA(bv, av1, acc2[1][nt]);
    }
  }
  #pragma unroll
  for (int mi = 0; mi < 2; ++mi) {
    const int mt = 2 * w + mi;
    #pragma unroll
    for (int nt = 0; nt < 2; ++nt) {
      const floatx4 bv = *(const floatx4*)(b2 + nt * 16 + hb);
      float o0 = fast_tanh(acc2[mi][nt][0] + bv[0]);
      float o1 = fast_tanh(acc2[mi][nt][1] + bv[1]);
      float o2 = fast_tanh(acc2[mi][nt][2] + bv[2]);
      float o3 = fast_tanh(acc2[mi][nt][3] + bv[3]);
      uint2 pk; pk.x = cvt_pk(o0, o1); pk.y = cvt_pk(o2, o3);
      *(uint2*)(x2out + (size_t)(r0 + mt * 16 + c) * 32 + nt * 16 + hb) = pk;
    }
  }
}

// ---------------------------------------------------------------------------
// Kernel 2 (R7): fused 2-layer GRU, single barrier per timestep, 32 seqs
// per block processed as two sequential 16-seq tiles with reused acc regs.
// Grid 768 (3 rounds of 1 block/CU). Wave J owns hidden cols [J*16,J*16+16).
// ---------------------------------------------------------------------------
__global__ __launch_bounds__(512, 2) void gru_res(
    const uint16_t* __restrict__ wpk, const uint16_t* __restrict__ x2,
    const float* __restrict__ bih0, const float* __restrict__ bhh0,
    const float* __restrict__ bih1, const float* __restrict__ bhh1,
    float* __restrict__ hout) {
  __shared__ uint16_t h0l[2][SEQB * 136];   // h0[t] double buffer (8704 B ea)
  __shared__ uint16_t h1l[2][SEQB * 136];   // h1[t] double buffer
  __shared__ float bias_l[8][128];          // R0,Z0,N0,H0,R1,Z1,N1,H1
  const int seq0 = blockIdx.x * SEQB;
  const int tid = threadIdx.x;
  const int J = tid >> 6, l = tid & 63, q = l >> 4, c = l & 15;
  const int lo8 = l * 8;

  // zero h1[-1]
  for (int i = tid; i < 2176; i += 512) ((uint32_t*)h1l[0])[i] = 0u;
  // bias table
  for (int i = tid; i < 1024; i += 512) {
    int g = i >> 7, k = i & 127;
    float v;
    if      (g == 0) v = bih0[k]       + bhh0[k];
    else if (g == 1) v = bih0[128 + k] + bhh0[128 + k];
    else if (g == 2) v = bih0[256 + k];
    else if (g == 3) v = bhh0[256 + k];
    else if (g == 4) v = bih1[k]       + bhh1[k];
    else if (g == 5) v = bih1[128 + k] + bhh1[128 + k];
    else if (g == 6) v = bih1[256 + k];
    else             v = bhh1[256 + k];
    bias_l[g][k] = v;
  }

  // ---- this wave's weight fragments (A-operands) into VGPRs (39 frags) ----
  bf16x8 wi0[3], wh0[3][4], wi1[3][4], wh1[3][4];
  #pragma unroll
  for (int g = 0; g < 3; ++g) {
    wi0[g] = ldf(wpk + PK_WIH0 + (g * 8 + J) * 512 + lo8);
    #pragma unroll
    for (int kb = 0; kb < 4; ++kb) {
      wh0[g][kb] = ldf(wpk + PK_WHH0 + ((g * 8 + J) * 4 + kb) * 512 + lo8);
      wi1[g][kb] = ldf(wpk + PK_WIH1 + ((g * 8 + J) * 4 + kb) * 512 + lo8);
      wh1[g][kb] = ldf(wpk + PK_WHH1 + ((g * 8 + J) * 4 + kb) * 512 + lo8);
    }
  }
  const int hb = J * 16 + 4 * q;     // this lane's 4 hidden cols (& bias idx)

  floatx4 h0m0 = (floatx4){0.f,0.f,0.f,0.f}, h0m1 = (floatx4){0.f,0.f,0.f,0.f};
  floatx4 h1m0 = (floatx4){0.f,0.f,0.f,0.f}, h1m1 = (floatx4){0.f,0.f,0.f,0.f};

  bf16x8 ax_0 = ldf(x2 + (size_t)(seq0 + c) * 32 + q * 8);                 // x[0] t0
  bf16x8 ax_1 = ldf(x2 + (size_t)(seq0 + 16 + c) * 32 + q * 8);            // x[0] t1
  __syncthreads();   // bias_l + zeroed h1l[0] visible

  // ---- prologue: L0[0] with h0[-1]=0 (skip Whh MFMAs) -> h0l[0] ----
  #define GRU_PRO(TI, AX, H0M)                                              \
  {                                                                         \
    floatx4 aR = *(const floatx4*)&bias_l[0][hb];                           \
    floatx4 aZ = *(const floatx4*)&bias_l[1][hb];                           \
    floatx4 aN = *(const floatx4*)&bias_l[2][hb];                           \
    floatx4 aH = *(const floatx4*)&bias_l[3][hb];                           \
    MFMA(wi0[0], AX, aR); MFMA(wi0[1], AX, aZ); MFMA(wi0[2], AX, aN);       \
    float o[4];                                                             \
    _Pragma("unroll")                                                       \
    for (int e = 0; e < 4; ++e) {                                           \
      float r  = fast_sigmoid(aR[e]);                                       \
      float zz = fast_sigmoid(aZ[e]);                                       \
      float nn = fast_tanh(aN[e] + r * aH[e]);                              \
      o[e] = nn - zz * nn;                                                  \
      H0M[e] = o[e];                                                        \
    }                                                                       \
    uint2 pk; pk.x = cvt_pk(o[0], o[1]); pk.y = cvt_pk(o[2], o[3]);         \
    *(uint2*)(h0l[0] + ((TI) * 16 + c) * 136 + hb) = pk;                    \
  }
  GRU_PRO(0, ax_0, h0m0)
  GRU_PRO(1, ax_1, h0m1)
  #undef GRU_PRO
  __syncthreads();

  // x[1] for phase t=0
  ax_0 = ldf(x2 + ((size_t)NSEQ + seq0 + c) * 32 + q * 8);
  ax_1 = ldf(x2 + ((size_t)NSEQ + seq0 + 16 + c) * 32 + q * 8);

  // per-tile phase body: {L1[t], L0[t+1]} for 16 seqs, accs reused across tiles
  #define GRU_TILE(TI, AX, H0M, H1M)                                        \
  {                                                                         \
    floatx4 aR1 = *(const floatx4*)&bias_l[4][hb];                          \
    floatx4 aZ1 = *(const floatx4*)&bias_l[5][hb];                          \
    floatx4 aN1 = *(const floatx4*)&bias_l[6][hb];                          \
    floatx4 aH1 = *(const floatx4*)&bias_l[7][hb];                          \
    floatx4 aR0 = *(const floatx4*)&bias_l[0][hb];                          \
    floatx4 aZ0 = *(const floatx4*)&bias_l[1][hb];                          \
    floatx4 aN0 = *(const floatx4*)&bias_l[2][hb];                          \
    floatx4 aH0 = *(const floatx4*)&bias_l[3][hb];                          \
    _Pragma("unroll")                                                       \
    for (int kb = 0; kb < 4; ++kb) {                                        \
      bf16x8 a0 = ldf(h0cur + ((TI) * 16 + c) * 136 + kb * 32 + q * 8);     \
      bf16x8 ah = ldf(h1prv + ((TI) * 16 + c) * 136 + kb * 32 + q * 8);     \
      MFMA(wi1[0][kb], a0, aR1); MFMA(wh1[0][kb], ah, aR1);                 \
      MFMA(wi1[1][kb], a0, aZ1); MFMA(wh1[1][kb], ah, aZ1);                 \
      MFMA(wi1[2][kb], a0, aN1); MFMA(wh1[2][kb], ah, aH1);                 \
      MFMA(wh0[0][kb], a0, aR0);                                            \
      MFMA(wh0[1][kb], a0, aZ0);                                            \
      MFMA(wh0[2][kb], a0, aH0);                                            \
    }                                                                       \
    MFMA(wi0[0], AX, aR0); MFMA(wi0[1], AX, aZ0); MFMA(wi0[2], AX, aN0);    \
    { /* L1 epilogue -> h1[t] */                                            \
      float o[4];                                                           \
      _Pragma("unroll")                                                     \
      for (int e = 0; e < 4; ++e) {                                         \
        float r  = fast_sigmoid(aR1[e]);                                    \
        float zz = fast_sigmoid(aZ1[e]);                                    \
        float nn = fast_tanh(aN1[e] + r * aH1[e]);                          \
        o[e] = nn + zz * (H1M[e] - nn);                                     \
        H1M[e] = o[e];                                                      \
      }                                                                     \
      uint2 pk; pk.x = cvt_pk(o[0], o[1]); pk.y = cvt_pk(o[2], o[3]);       \
      *(uint2*)(h1cur + ((TI) * 16 + c) * 136 + hb) = pk;                   \
    }                                                                       \
    { /* L0 epilogue -> h0[t+1] */                                          \
      float o[4];                                                           \
      _Pragma("unroll")                                                     \
      for (int e = 0; e < 4; ++e) {                                         \
        float r  = fast_sigmoid(aR0[e]);                                    \
        float zz = fast_sigmoid(aZ0[e]);                                    \
        float nn = fast_tanh(aN0[e] + r * aH0[e]);                          \
        o[e] = nn + zz * (H0M[e] - nn);                                     \
        H0M[e] = o[e];                                                      \
      }                                                                     \
      uint2 pk; pk.x = cvt_pk(o[0], o[1]); pk.y = cvt_pk(o[2], o[3]);       \
      *(uint2*)(h0nxt + ((TI) * 16 + c) * 136 + hb) = pk;                   \
    }                                                                       \
  }

  #pragma unroll 1
  for (int t = 0; t < TSTEPS; ++t) {
    const uint16_t* h0cur = h0l[t & 1];          // h0[t]
    const uint16_t* h1prv = h1l[t & 1];          // h1[t-1]
    uint16_t* h0nxt = h0l[(t + 1) & 1];          // h0[t+1]
    uint16_t* h1cur = h1l[(t + 1) & 1];          // h1[t]
    const int tnx = (t + 2 < TSTEPS) ? t + 2 : TSTEPS - 1;
    bf16x8 axn_0 = ldf(x2 + ((size_t)tnx * NSEQ + seq0 + c) * 32 + q * 8);
    bf16x8 axn_1 = ldf(x2 + ((size_t)tnx * NSEQ + seq0 + 16 + c) * 32 + q * 8);

    GRU_TILE(0, ax_0, h0m0, h1m0)
    __builtin_amdgcn_sched_barrier(0);   // pin tile split: acc regs reused
    GRU_TILE(1, ax_1, h0m1, h1m1)

    __syncthreads();
    ax_0 = axn_0; ax_1 = axn_1;
  }
  #undef GRU_TILE

  *(floatx4*)(hout + (size_t)(seq0 + c) * 128 + hb) = h1m0;
  *(floatx4*)(hout + (size_t)(seq0 + 16 + c) * 128 + hb) = h1m1;
}

// ---------------------------------------------------------------------------
// Kernel 3: mean over routes + candidate head + fc1/fc2/fc3 (unchanged)
// ---------------------------------------------------------------------------
__global__ __launch_bounds__(192) void final_kernel(
    const float* __restrict__ hout, const float* __restrict__ cands,
    const float* __restrict__ cw, const float* __restrict__ cb,
    const float* __restrict__ f1w, const float* __restrict__ f1b,
    const float* __restrict__ f2w, const float* __restrict__ f2b,
    const float* __restrict__ f3w, const float* __restrict__ f3b,
    float* __restrict__ out) {
  __shared__ float hc[192];
  __shared__ float v1[128];
  __shared__ float v2[128];
  __shared__ float red[128];
  const int b = blockIdx.x, tid = threadIdx.x;
  if (tid < 128) {
    float s = 0.f;
    const float* hp = hout + (size_t)(b * 48) * 128 + tid;
    #pragma unroll 4
    for (int r = 0; r < 48; ++r) s += hp[r * 128];
    hc[tid] = s * (1.0f / 48.0f);
  } else {
    int j = tid - 128;
    float s = cb[j];
    const float* cp = cands + b * 72;
    #pragma unroll 8
    for (int k = 0; k < 72; ++k) s += cp[k] * cw[k * 64 + j];
    hc[128 + j] = s;
  }
  __syncthreads();
  if (tid < 128) {
    float s = f1b[tid];
    for (int k = 0; k < 192; ++k) s += hc[k] * f1w[k * 128 + tid];
    v1[tid] = fast_tanh(s);
  }
  __syncthreads();
  if (tid < 128) {
    float s = f2b[tid];
    for (int k = 0; k < 128; ++k) s += v1[k] * f2w[k * 128 + tid];
    v2[tid] = fast_tanh(s);
  }
  __syncthreads();
  if (tid < 128) red[tid] = v2[tid] * f3w[tid];
  __syncthreads();
  if (tid < 64) {
    float s = red[tid] + red[tid + 64];
    s += __shfl_down(s, 32);
    s += __shfl_down(s, 16);
    s += __shfl_down(s, 8);
    s += __shfl_down(s, 4);
    s += __shfl_down(s, 2);
    s += __shfl_down(s, 1);
    if (tid == 0) out[b] = s + f3b[0];
  }
}

// ---------------------------------------------------------------------------
extern "C" void kernel_launch(void* const* d_in, const int* in_sizes, int n_in,
                              void* d_out, int out_size, void* d_ws, size_t ws_size,
                              hipStream_t stream) {
  const float* cand  = (const float*)d_in[0];
  const float* cust  = (const float*)d_in[1];
  const float* w1    = (const float*)d_in[2];
  const float* b1    = (const float*)d_in[3];
  const float* w2    = (const float*)d_in[4];
  const float* b2    = (const float*)d_in[5];
  const float* wih0  = (const float*)d_in[6];
  const float* whh0  = (const float*)d_in[7];
  const float* bih0  = (const float*)d_in[8];
  const float* bhh0  = (const float*)d_in[9];
  const float* wih1  = (const float*)d_in[10];
  const float* whh1  = (const float*)d_in[11];
  const float* bih1  = (const float*)d_in[12];
  const float* bhh1  = (const float*)d_in[13];
  const float* cw    = (const float*)d_in[14];
  const float* cb    = (const float*)d_in[15];
  const float* f1w   = (const float*)d_in[16];
  const float* f1b   = (const float*)d_in[17];
  const float* f2w   = (const float*)d_in[18];
  const float* f2b   = (const float*)d_in[19];
  const float* f3w   = (const float*)d_in[20];
  const float* f3b   = (const float*)d_in[21];

  uint16_t* wsp = (uint16_t*)d_ws;
  uint16_t* x2p = wsp + X2_EL;
  float* hout = (float*)((char*)d_ws + HOUT_BYTE);
  float* outp = (float*)d_out;

  pack_weights<<<(PK_END + 255) / 256, 256, 0, stream>>>(w1, w2, wih0, whh0, wih1, whh1, wsp);
  mlp_kernel<<<(NSEQ * TSTEPS) / 128, 256, 0, stream>>>(cust, b1, b2, wsp, x2p);
  gru_res<<<NSEQ / SEQB, 512, 0, stream>>>(wsp, x2p, bih0, bhh0, bih1, bhh1, hout);
  final_kernel<<<512, 192, 0, stream>>>(hout, cand, cw, cb, f1w, f1b, f2w, f2b, f3w, f3b, outp);
}